// Round 1
// baseline (65.132 us; speedup 1.0000x reference)
//
#include <hip/hip_runtime.h>

#define NB 32
#define TS 300
#define NBATCH 16384
#define DTF (1.0f/300.0f)
#define A_ELEMS (NBATCH*2*TS)   /* 9,830,400 */
#define TC 16

// ---------------- kernel A: phi table [300][32] ----------------
__global__ __launch_bounds__(320) void k_phi(const float* __restrict__ c,
                                             const float* __restrict__ s2,
                                             float* __restrict__ phi) {
    __shared__ float xs[TS];
    if (threadIdx.x == 0) {
        float x = 1.0f;
        for (int i = 0; i < TS; ++i) { x = x - x * DTF; xs[i] = x; }
    }
    __syncthreads();
    const int t = threadIdx.x;
    if (t < TS) {
        const float x = xs[t];
        float ps[NB]; float s = 0.0f;
        #pragma unroll
        for (int n = 0; n < NB; ++n) {
            float d = x - c[n];
            float p = __expf(-0.5f * d * d / s2[n]);
            ps[n] = p; s += p;
        }
        const float inv = x / s;
        #pragma unroll
        for (int n = 0; n < NB; n += 4) {
            *(float4*)(phi + t*NB + n) =
                make_float4(ps[n]*inv, ps[n+1]*inv, ps[n+2]*inv, ps[n+3]*inv);
        }
    }
}

// ---------------- kernel B: MLP heads ----------------
// wave-per-batch; lane j register-caches fc2cat row j (a1) and row 64+(j%6) (a2).
// rows: 0..65 ndp_wg, 66..67 sigma head, 68..69 value head.
__global__ __launch_bounds__(256) void k_head(
    const float* __restrict__ state,
    const float* __restrict__ fc1_w, const float* __restrict__ fc1_b,
    const float* __restrict__ fc2m_w, const float* __restrict__ fc2m_b,
    const float* __restrict__ sig_w, const float* __restrict__ sig_b,
    const float* __restrict__ val_w, const float* __restrict__ val_b,
    float* __restrict__ sig_out, float* __restrict__ pbuf, float* __restrict__ wbuf)
{
    __shared__ float f1[64*4];
    __shared__ float hls[4][64];
    const int tid = threadIdx.x;
    const int wv_ = tid >> 6;   // wave in block
    const int j   = tid & 63;   // lane
    if (tid < 64) {
        f1[tid*4+0] = fc1_w[tid*3+0];
        f1[tid*4+1] = fc1_w[tid*3+1];
        f1[tid*4+2] = fc1_w[tid*3+2];
        f1[tid*4+3] = fc1_b[tid];
    }
    const int r2 = 64 + (j % 6);
    const float* w2src = (r2 < 66) ? (fc2m_w + r2*64)
                       : (r2 < 68) ? (sig_w + (r2-66)*64)
                       : (val_w + (r2-68)*64);
    float wr[64], w2[64];
    #pragma unroll
    for (int k = 0; k < 64; k += 4) {
        float4 a  = *(const float4*)(fc2m_w + j*64 + k);
        wr[k+0]=a.x; wr[k+1]=a.y; wr[k+2]=a.z; wr[k+3]=a.w;
        float4 b4 = *(const float4*)(w2src + k);
        w2[k+0]=b4.x; w2[k+1]=b4.y; w2[k+2]=b4.z; w2[k+3]=b4.w;
    }
    const float bias1 = fc2m_b[j];
    const float bias2 = (r2 < 66) ? fc2m_b[r2] : (r2 < 68) ? sig_b[r2-66] : val_b[r2-68];
    __syncthreads();

    for (int it = 0; it < 4; ++it) {
        const int b = (blockIdx.x << 4) + (it << 2) + wv_;
        const float s0 = state[b*3+0], s1 = state[b*3+1], s2v = state[b*3+2];
        float4 fw = *(const float4*)(f1 + j*4);
        float pre = fw.x*s0 + fw.y*s1 + fw.z*s2v + fw.w;
        float e = __expf(2.0f * pre);
        float h = (1.0f - 2.0f/(e + 1.0f)) * 0.1f;   // tanh, overflow-safe
        hls[wv_][j] = h;
        __syncthreads();
        float a1 = bias1, a1b = 0.0f, a2 = bias2, a2b = 0.0f;
        #pragma unroll
        for (int k = 0; k < 64; k += 4) {
            float4 hv = *(const float4*)(&hls[wv_][k]);   // broadcast read
            a1  = fmaf(wr[k+0], hv.x, a1 );
            a1b = fmaf(wr[k+1], hv.y, a1b);
            a1  = fmaf(wr[k+2], hv.z, a1 );
            a1b = fmaf(wr[k+3], hv.w, a1b);
            a2  = fmaf(w2[k+0], hv.x, a2 );
            a2b = fmaf(w2[k+1], hv.y, a2b);
            a2  = fmaf(w2[k+2], hv.z, a2 );
            a2b = fmaf(w2[k+3], hv.w, a2b);
        }
        a1 += a1b; a2 += a2b;
        // epilogue
        float az = __shfl(a2, 1, 64);                 // raw row 65
        az = fminf(fmaxf(az, 0.5f), 30.0f);
        float vvl = __shfl(a2, 4 + (j & 1), 64);      // value rows 68/69
        if (j >= 2) wbuf[b*64 + j - 2]  = a1;         // w elems 0..61 (rows 2..63)
        else        wbuf[b*64 + 62 + j] = a2;         // w elems 62,63 (rows 64,65 raw)
        if (j == 2 || j == 3) {
            sig_out[b*2 + j - 2] = 1.0f / (1.0f + __expf(-a2)) + 0.001f;
        }
        if (j < 2) {
            float y0 = (j == 0) ? s0 : s1;
            *(float4*)(pbuf + (b*2 + j)*4) = make_float4(a1, a1 - y0, az, vvl);
        }
        __syncthreads();
    }
}

// ---------------- kernel C: DMP rollout ----------------
// 4 lanes per channel, per-lane partial linear state (y_q,z_q); sum only at flush.
// z' = z + c0 + K*p - Bc*z - A*y ;  y' = y + DT*z ;  a[t] = z_old*DT
__global__ __launch_bounds__(256) void k_rollout(
    const float* __restrict__ phi_g, const float* __restrict__ pbuf,
    const float* __restrict__ wbuf, float* __restrict__ a_out,
    float* __restrict__ v_out)
{
    __shared__ float phi[TS*NB];        // 38400 B
    __shared__ float tile[TC][256];     // 16384 B
    const int tid = threadIdx.x;
    for (int i = tid; i < TS*NB/4; i += 256)
        ((float4*)phi)[i] = ((const float4*)phi_g)[i];

    const int ch = tid >> 2;            // channel within block (0..63)
    const int q  = tid & 3;             // lane quarter
    const int m  = (blockIdx.x << 6) + ch;
    const float4 pp = *(const float4*)(pbuf + m*4);   // {goal, kfac, az, v}
    const float az = pp.z;
    const float A  = DTF * az * az * 0.25f;           // DT*az*bz
    const float Bc = DTF * az;
    const float K  = DTF * pp.y;
    const float c0 = (q == 0) ? A * pp.x : 0.0f;
    float wv[8];
    {
        float4 w0 = *(const float4*)(wbuf + m*32 + q*8);
        float4 w1 = *(const float4*)(wbuf + m*32 + q*8 + 4);
        wv[0]=w0.x; wv[1]=w0.y; wv[2]=w0.z; wv[3]=w0.w;
        wv[4]=w1.x; wv[5]=w1.y; wv[6]=w1.z; wv[7]=w1.w;
    }
    float y = (q == 0) ? (pp.x - pp.y) : 0.0f;   // goal - kfac = y0
    float z = (q == 0) ? 0.01f : 0.0f;
    __syncthreads();

    const float* ph = phi + q*8;
    const float4 vsplat = make_float4(pp.w, pp.w, pp.w, pp.w);

    int t0 = 0;
    for (int chunk = 0; chunk < 18; ++chunk) {
        #pragma unroll
        for (int i = 0; i < TC; ++i) {
            const float* pr = ph + (t0 + i)*NB;
            float4 p0v = *(const float4*)(pr);
            float4 p1v = *(const float4*)(pr + 4);
            float pa = wv[0]*p0v.x, pb = wv[1]*p0v.y;
            pa = fmaf(wv[2], p0v.z, pa); pb = fmaf(wv[3], p0v.w, pb);
            pa = fmaf(wv[4], p1v.x, pa); pb = fmaf(wv[5], p1v.y, pb);
            pa = fmaf(wv[6], p1v.z, pa); pb = fmaf(wv[7], p1v.w, pb);
            float p = pa + pb;
            float aval = z * DTF;
            float u = z + c0;
            u = fmaf(K, p, u);
            u = fmaf(-Bc, z, u);
            float zn = fmaf(-A, y, u);
            y += aval;
            z = zn;
            tile[i][tid] = aval;
        }
        __syncthreads();
        {
            float4 s0 = *(const float4*)(&tile[q*4+0][ch*4]);
            float4 s1 = *(const float4*)(&tile[q*4+1][ch*4]);
            float4 s2 = *(const float4*)(&tile[q*4+2][ch*4]);
            float4 s3 = *(const float4*)(&tile[q*4+3][ch*4]);
            float r0 = (s0.x+s0.y)+(s0.z+s0.w);
            float r1 = (s1.x+s1.y)+(s1.z+s1.w);
            float r2 = (s2.x+s2.y)+(s2.z+s2.w);
            float r3 = (s3.x+s3.y)+(s3.z+s3.w);
            const int ob = m*TS + t0 + q*4;
            *(float4*)(a_out + ob) = make_float4(r0, r1, r2, r3);
            *(float4*)(v_out + ob) = vsplat;
        }
        __syncthreads();
        t0 += TC;
    }
    // tail: 12 steps (t = 288..299)
    #pragma unroll
    for (int i = 0; i < 12; ++i) {
        const float* pr = ph + (288 + i)*NB;
        float4 p0v = *(const float4*)(pr);
        float4 p1v = *(const float4*)(pr + 4);
        float pa = wv[0]*p0v.x, pb = wv[1]*p0v.y;
        pa = fmaf(wv[2], p0v.z, pa); pb = fmaf(wv[3], p0v.w, pb);
        pa = fmaf(wv[4], p1v.x, pa); pb = fmaf(wv[5], p1v.y, pb);
        pa = fmaf(wv[6], p1v.z, pa); pb = fmaf(wv[7], p1v.w, pb);
        float p = pa + pb;
        float aval = z * DTF;
        float u = z + c0;
        u = fmaf(K, p, u);
        u = fmaf(-Bc, z, u);
        float zn = fmaf(-A, y, u);
        y += aval;
        z = zn;
        tile[i][tid] = aval;
    }
    __syncthreads();
    if (q < 3) {
        float4 s0 = *(const float4*)(&tile[q*4+0][ch*4]);
        float4 s1 = *(const float4*)(&tile[q*4+1][ch*4]);
        float4 s2 = *(const float4*)(&tile[q*4+2][ch*4]);
        float4 s3 = *(const float4*)(&tile[q*4+3][ch*4]);
        float r0 = (s0.x+s0.y)+(s0.z+s0.w);
        float r1 = (s1.x+s1.y)+(s1.z+s1.w);
        float r2 = (s2.x+s2.y)+(s2.z+s2.w);
        float r3 = (s3.x+s3.y)+(s3.z+s3.w);
        const int ob = m*TS + 288 + q*4;
        *(float4*)(a_out + ob) = make_float4(r0, r1, r2, r3);
        *(float4*)(v_out + ob) = vsplat;
    }
}

extern "C" void kernel_launch(void* const* d_in, const int* in_sizes, int n_in,
                              void* d_out, int out_size, void* d_ws, size_t ws_size,
                              hipStream_t stream) {
    (void)in_sizes; (void)n_in; (void)out_size; (void)ws_size;
    const float* state  = (const float*)d_in[0];
    const float* fc1_w  = (const float*)d_in[1];
    const float* fc1_b  = (const float*)d_in[2];
    const float* fc2m_w = (const float*)d_in[3];
    const float* fc2m_b = (const float*)d_in[4];
    const float* sig_w  = (const float*)d_in[5];
    const float* sig_b  = (const float*)d_in[6];
    const float* val_w  = (const float*)d_in[7];
    const float* val_b  = (const float*)d_in[8];
    const float* dmp_c  = (const float*)d_in[9];
    const float* dmp_s2 = (const float*)d_in[10];

    float* out     = (float*)d_out;
    float* a_out   = out;
    float* sig_out = out + A_ELEMS;
    float* v_out   = out + A_ELEMS + NBATCH*2;

    float* ws   = (float*)d_ws;
    float* phi  = ws;                      // 9600 floats
    float* pbuf = ws + 16384;              // 131072 floats {goal,kfac,az,v} per channel
    float* wbuf = ws + 16384 + 131072;     // 1048576 floats, [M][32]

    k_phi<<<dim3(1), dim3(320), 0, stream>>>(dmp_c, dmp_s2, phi);
    k_head<<<dim3(1024), dim3(256), 0, stream>>>(state, fc1_w, fc1_b, fc2m_w, fc2m_b,
                                                 sig_w, sig_b, val_w, val_b,
                                                 sig_out, pbuf, wbuf);
    k_rollout<<<dim3(512), dim3(256), 0, stream>>>(phi, pbuf, wbuf, a_out, v_out);
}

// Round 2
// 46.632 us; speedup vs baseline: 1.3967x; 1.3967x over previous
//
#include <hip/hip_runtime.h>
#include <hip/hip_bf16.h>

#define NB 32
#define TS 300
#define TSP 304
#define NBATCH 16384
#define DTF (1.0f/300.0f)
#define A_ELEMS (NBATCH*2*TS)   /* 9,830,400 */

typedef __attribute__((ext_vector_type(8))) short bf16x8;
typedef __attribute__((ext_vector_type(4))) float f32x4;

static __device__ __forceinline__ ushort f2bf(float f) {
    union { __hip_bfloat16 h; ushort u; } cv;
    cv.h = __float2bfloat16(f);
    return cv.u;
}

// ---------------- kernel B: MLP heads + fused phi table ----------------
// blocks 0..1023: wave-per-batch MLP. block 1024: bf16 phi table [304][32].
__global__ __launch_bounds__(256) void k_head(
    const float* __restrict__ state,
    const float* __restrict__ fc1_w, const float* __restrict__ fc1_b,
    const float* __restrict__ fc2m_w, const float* __restrict__ fc2m_b,
    const float* __restrict__ sig_w, const float* __restrict__ sig_b,
    const float* __restrict__ val_w, const float* __restrict__ val_b,
    const float* __restrict__ dmp_c, const float* __restrict__ dmp_s2,
    float* __restrict__ sig_out, float* __restrict__ pbuf, float* __restrict__ wbuf,
    ushort* __restrict__ phiB)
{
    if (blockIdx.x == 1024) {
        // phi[t][n] = psi_n(x_t) * x_t / sum_n psi_n(x_t), x_t = (1-DT)^(t+1), bf16.
        const float l2 = log2f(1.0f - DTF);
        for (int t = threadIdx.x; t < TSP; t += 256) {
            ushort row[NB];
            if (t < TS) {
                const float x = exp2f((float)(t + 1) * l2);
                float ps[NB]; float s = 0.0f;
                #pragma unroll
                for (int n = 0; n < NB; ++n) {
                    float d = x - dmp_c[n];
                    float p = __expf(-0.5f * d * d / dmp_s2[n]);
                    ps[n] = p; s += p;
                }
                const float inv = x / s;
                #pragma unroll
                for (int n = 0; n < NB; ++n) row[n] = f2bf(ps[n] * inv);
            } else {
                #pragma unroll
                for (int n = 0; n < NB; ++n) row[n] = 0;   // zero-pad rows 300..303
            }
            uint4* dst = (uint4*)(phiB + t*NB);
            #pragma unroll
            for (int q4 = 0; q4 < 4; ++q4) {
                union { ushort us[8]; uint4 v; } pk;
                #pragma unroll
                for (int e = 0; e < 8; ++e) pk.us[e] = row[q4*8 + e];
                dst[q4] = pk.v;
            }
        }
        return;
    }

    __shared__ float f1[64*4];
    __shared__ float hls[4][64];
    const int tid = threadIdx.x;
    const int wv_ = tid >> 6;
    const int j   = tid & 63;
    if (tid < 64) {
        f1[tid*4+0] = fc1_w[tid*3+0];
        f1[tid*4+1] = fc1_w[tid*3+1];
        f1[tid*4+2] = fc1_w[tid*3+2];
        f1[tid*4+3] = fc1_b[tid];
    }
    const int r2 = 64 + (j % 6);
    const float* w2src = (r2 < 66) ? (fc2m_w + r2*64)
                       : (r2 < 68) ? (sig_w + (r2-66)*64)
                       : (val_w + (r2-68)*64);
    float wr[64], w2[64];
    #pragma unroll
    for (int k = 0; k < 64; k += 4) {
        float4 a  = *(const float4*)(fc2m_w + j*64 + k);
        wr[k+0]=a.x; wr[k+1]=a.y; wr[k+2]=a.z; wr[k+3]=a.w;
        float4 b4 = *(const float4*)(w2src + k);
        w2[k+0]=b4.x; w2[k+1]=b4.y; w2[k+2]=b4.z; w2[k+3]=b4.w;
    }
    const float bias1 = fc2m_b[j];
    const float bias2 = (r2 < 66) ? fc2m_b[r2] : (r2 < 68) ? sig_b[r2-66] : val_b[r2-68];
    __syncthreads();

    for (int it = 0; it < 4; ++it) {
        const int b = (blockIdx.x << 4) + (it << 2) + wv_;
        const float s0 = state[b*3+0], s1 = state[b*3+1], s2v = state[b*3+2];
        float4 fw = *(const float4*)(f1 + j*4);
        float pre = fw.x*s0 + fw.y*s1 + fw.z*s2v + fw.w;
        float e = __expf(2.0f * pre);
        float h = (1.0f - 2.0f/(e + 1.0f)) * 0.1f;   // tanh, overflow-safe
        hls[wv_][j] = h;
        __syncthreads();
        float a1 = bias1, a1b = 0.0f, a2 = bias2, a2b = 0.0f;
        #pragma unroll
        for (int k = 0; k < 64; k += 4) {
            float4 hv = *(const float4*)(&hls[wv_][k]);
            a1  = fmaf(wr[k+0], hv.x, a1 );
            a1b = fmaf(wr[k+1], hv.y, a1b);
            a1  = fmaf(wr[k+2], hv.z, a1 );
            a1b = fmaf(wr[k+3], hv.w, a1b);
            a2  = fmaf(w2[k+0], hv.x, a2 );
            a2b = fmaf(w2[k+1], hv.y, a2b);
            a2  = fmaf(w2[k+2], hv.z, a2 );
            a2b = fmaf(w2[k+3], hv.w, a2b);
        }
        a1 += a1b; a2 += a2b;
        float az = __shfl(a2, 1, 64);                 // raw row 65
        az = fminf(fmaxf(az, 0.5f), 30.0f);
        float vvl = __shfl(a2, 4 + (j & 1), 64);      // value rows 68/69
        if (j >= 2) wbuf[b*64 + j - 2]  = a1;
        else        wbuf[b*64 + 62 + j] = a2;
        if (j == 2 || j == 3) {
            sig_out[b*2 + j - 2] = 1.0f / (1.0f + __expf(-a2)) + 0.001f;
        }
        if (j < 2) {
            float y0 = (j == 0) ? s0 : s1;
            *(float4*)(pbuf + (b*2 + j)*4) = make_float4(a1, a1 - y0, az, vvl);
        }
        __syncthreads();
    }
}

// ---------------- kernel C: DMP rollout, MFMA-fed forcing ----------------
// Wave = 16 channels x 4 time-groups. Per 16-step chunk: one
// mfma_f32_16x16x32_bf16 computes F[t][ch] (A=phi chunk via coalesced 16B
// global load, B=w in regs). Lane group g injects force on its 4 owned
// steps only; linear superposition over groups; partials summed at the
// tile flush (pad 260 -> 2-way, free).
__global__ __launch_bounds__(256) void k_rollout(
    const ushort* __restrict__ phiB, const float* __restrict__ pbuf,
    const float* __restrict__ wbuf, float* __restrict__ a_out,
    float* __restrict__ v_out)
{
    __shared__ float tile[16][260];
    const int tid = threadIdx.x;
    const int wv = tid >> 6;
    const int l  = tid & 63;
    const int ch = l & 15;
    const int g  = l >> 4;
    const int m  = (blockIdx.x << 6) + (wv << 4) + ch;

    const float4 pp = *(const float4*)(pbuf + m*4);   // {goal, kfac, az, v}
    const float az = pp.z;
    const float Ac = DTF * az * az * 0.25f;
    const float Bc = DTF * az;
    const float Kc = DTF * pp.y;
    const float c0 = (g == 0) ? Ac * pp.x : 0.0f;
    float y = (g == 0) ? (pp.x - pp.y) : 0.0f;        // y0
    float z = (g == 0) ? 0.01f : 0.0f;

    // B-frag: lane holds w[ch][k], k = g*8..g*8+7  (B[k][col] layout)
    bf16x8 wb;
    {
        const float* wp = wbuf + m*NB + g*8;
        union { bf16x8 v; ushort u[8]; } uw;
        #pragma unroll
        for (int jj = 0; jj < 8; ++jj) uw.u[jj] = f2bf(wp[jj]);
        wb = uw.v;
    }
    // A-frag: lane holds phi[t0 + ch][k], k = g*8..g*8+7 (A[row][k] layout)
    const bf16x8* ap = (const bf16x8*)(phiB + ch*NB + g*8);  // +64 units/chunk

    const float fv = pp.w;
    const f32x4 zacc = {0.0f, 0.0f, 0.0f, 0.0f};
    bf16x8 af = ap[0];

    for (int c = 0; c < 19; ++c) {
        f32x4 facc = __builtin_amdgcn_mfma_f32_16x16x32_bf16(af, wb, zacc, 0, 0, 0);
        if (c < 18) af = ap[(c + 1) * 64];            // prefetch next A-frag
        const int t0 = c * 16;
        #pragma unroll
        for (int i = 0; i < 16; ++i) {
            float f = (g == (i >> 2)) ? facc[i & 3] : 0.0f;
            float aval = z * DTF;
            tile[i][tid] = aval;
            float u = z + c0;
            u = fmaf(Kc, f, u);
            u = fmaf(-Bc, z, u);
            z = fmaf(-Ac, y, u);
            y += aval;
        }
        // flush: lane stores channel m, t-quad g*4 (sum 4 group partials)
        if (c < 18 || g < 3) {
            const int colb = (wv << 6) + ch;
            float s0 = 0.f, s1 = 0.f, s2 = 0.f, s3 = 0.f;
            #pragma unroll
            for (int gg = 0; gg < 4; ++gg) {
                const int cc = colb + (gg << 4);
                s0 += tile[(g << 2) + 0][cc];
                s1 += tile[(g << 2) + 1][cc];
                s2 += tile[(g << 2) + 2][cc];
                s3 += tile[(g << 2) + 3][cc];
            }
            const int ob = m * TS + t0 + (g << 2);
            *(float4*)(a_out + ob) = make_float4(s0, s1, s2, s3);
            *(float4*)(v_out + ob) = make_float4(fv, fv, fv, fv);
        }
    }
}

extern "C" void kernel_launch(void* const* d_in, const int* in_sizes, int n_in,
                              void* d_out, int out_size, void* d_ws, size_t ws_size,
                              hipStream_t stream) {
    (void)in_sizes; (void)n_in; (void)out_size; (void)ws_size;
    const float* state  = (const float*)d_in[0];
    const float* fc1_w  = (const float*)d_in[1];
    const float* fc1_b  = (const float*)d_in[2];
    const float* fc2m_w = (const float*)d_in[3];
    const float* fc2m_b = (const float*)d_in[4];
    const float* sig_w  = (const float*)d_in[5];
    const float* sig_b  = (const float*)d_in[6];
    const float* val_w  = (const float*)d_in[7];
    const float* val_b  = (const float*)d_in[8];
    const float* dmp_c  = (const float*)d_in[9];
    const float* dmp_s2 = (const float*)d_in[10];

    float* out     = (float*)d_out;
    float* a_out   = out;
    float* sig_out = out + A_ELEMS;
    float* v_out   = out + A_ELEMS + NBATCH*2;

    float* ws    = (float*)d_ws;
    ushort* phiB = (ushort*)ws;            // 9728 ushorts (19456 B)
    float* pbuf  = ws + 8192;              // 131072 floats {goal,kfac,az,v}/channel
    float* wbuf  = ws + 8192 + 131072;     // 1,048,576 floats, [M][32]

    k_head<<<dim3(1025), dim3(256), 0, stream>>>(state, fc1_w, fc1_b, fc2m_w, fc2m_b,
                                                 sig_w, sig_b, val_w, val_b,
                                                 dmp_c, dmp_s2,
                                                 sig_out, pbuf, wbuf, phiB);
    k_rollout<<<dim3(512), dim3(256), 0, stream>>>(phiB, pbuf, wbuf, a_out, v_out);
}

// Round 3
// 33.946 us; speedup vs baseline: 1.9187x; 1.3737x over previous
//
#include <hip/hip_runtime.h>
#include <hip/hip_bf16.h>

#define NB 32
#define TS 300
#define TSP 304
#define NBATCH 16384
#define DTF (1.0f/300.0f)
#define A_ELEMS (NBATCH*2*TS)   /* 9,830,400 */

typedef __attribute__((ext_vector_type(8))) short bf16x8;
typedef __attribute__((ext_vector_type(4))) float f32x4;

static __device__ __forceinline__ ushort f2bf(float f) {
    union { __hip_bfloat16 h; ushort u; } cv;
    cv.h = __float2bfloat16(f);
    return cv.u;
}
static __device__ __forceinline__ float rdlane(float v, int lane) {
    return __int_as_float(__builtin_amdgcn_readlane(__float_as_int(v), lane));
}

// ---------------- kernel B: MLP heads + fused phi table ----------------
// blocks 0..511: 4 waves x 8 batches each, weights LDS-staged (quad-XOR
// swizzle -> conflict-free b128 row reads), h broadcast via v_readlane
// (wave-uniform batch), no barriers in the batch loop.
// block 512: bf16 phi table [304][32] (rows 300..303 zero-padded).
__global__ __launch_bounds__(256) void k_head(
    const float* __restrict__ state,
    const float* __restrict__ fc1_w, const float* __restrict__ fc1_b,
    const float* __restrict__ fc2m_w, const float* __restrict__ fc2m_b,
    const float* __restrict__ sig_w, const float* __restrict__ sig_b,
    const float* __restrict__ val_w, const float* __restrict__ val_b,
    const float* __restrict__ dmp_c, const float* __restrict__ dmp_s2,
    float* __restrict__ sig_out, float* __restrict__ pbuf,
    ushort* __restrict__ wbuf16, ushort* __restrict__ phiB)
{
    if (blockIdx.x == 512) {
        const float l2 = log2f(1.0f - DTF);
        for (int t = threadIdx.x; t < TSP; t += 256) {
            ushort row[NB];
            if (t < TS) {
                const float x = exp2f((float)(t + 1) * l2);
                float ps[NB]; float s = 0.0f;
                #pragma unroll
                for (int n = 0; n < NB; ++n) {
                    float d = x - dmp_c[n];
                    float p = __expf(-0.5f * d * d / dmp_s2[n]);
                    ps[n] = p; s += p;
                }
                const float inv = x / s;
                #pragma unroll
                for (int n = 0; n < NB; ++n) row[n] = f2bf(ps[n] * inv);
            } else {
                #pragma unroll
                for (int n = 0; n < NB; ++n) row[n] = 0;
            }
            uint4* dst = (uint4*)(phiB + t*NB);
            #pragma unroll
            for (int q4 = 0; q4 < 4; ++q4) {
                union { ushort us[8]; uint4 v; } pk;
                #pragma unroll
                for (int e = 0; e < 8; ++e) pk.us[e] = row[q4*8 + e];
                dst[q4] = pk.v;
            }
        }
        return;
    }

    __shared__ float wlds[70*64];   // 17.9 KB, quad-XOR swizzled rows
    __shared__ float f1[64*4];
    const int tid = threadIdx.x;
    const int wv_ = tid >> 6;
    const int j   = tid & 63;

    // coalesced global -> swizzled LDS (once per block)
    for (int i = tid; i < 70*64; i += 256) {
        const int row = i >> 6, col = i & 63;
        float v;
        if (row < 66)      v = fc2m_w[i];
        else if (row < 68) v = sig_w[(row-66)*64 + col];
        else               v = val_w[(row-68)*64 + col];
        const int q = col >> 2, e = col & 3;
        wlds[row*64 + (((q ^ (row & 15)) << 2) | e)] = v;
    }
    if (tid < 64) {
        f1[tid*4+0] = fc1_w[tid*3+0];
        f1[tid*4+1] = fc1_w[tid*3+1];
        f1[tid*4+2] = fc1_w[tid*3+2];
        f1[tid*4+3] = fc1_b[tid];
    }
    __syncthreads();

    const int r2 = 64 + (j % 6);
    float wr[64], w2[64];
    #pragma unroll
    for (int q = 0; q < 16; ++q) {
        float4 a  = *(const float4*)(wlds + j*64  + ((q ^ (j  & 15)) << 2));
        wr[q*4+0]=a.x; wr[q*4+1]=a.y; wr[q*4+2]=a.z; wr[q*4+3]=a.w;
        float4 b4 = *(const float4*)(wlds + r2*64 + ((q ^ (r2 & 15)) << 2));
        w2[q*4+0]=b4.x; w2[q*4+1]=b4.y; w2[q*4+2]=b4.z; w2[q*4+3]=b4.w;
    }
    const float bias1 = fc2m_b[j];
    const float bias2 = (r2 < 66) ? fc2m_b[r2] : (r2 < 68) ? sig_b[r2-66] : val_b[r2-68];
    const float4 fw = *(const float4*)(f1 + j*4);

    // prefetch this wave's 8 batches of state (24 floats) into lanes 0..23
    const int bbase = (blockIdx.x << 5) + (wv_ << 3);
    float sreg = (j < 24) ? state[bbase*3 + j] : 0.0f;

    for (int it = 0; it < 8; ++it) {
        const int b = bbase + it;
        const float s0  = rdlane(sreg, it*3+0);
        const float s1  = rdlane(sreg, it*3+1);
        const float s2v = rdlane(sreg, it*3+2);
        float pre = fmaf(fw.x, s0, fmaf(fw.y, s1, fmaf(fw.z, s2v, fw.w)));
        float e = __expf(2.0f * pre);
        float h = (1.0f - 2.0f/(e + 1.0f)) * 0.1f;   // tanh, overflow-safe
        float a1 = bias1, a1b = 0.0f, a2 = bias2, a2b = 0.0f;
        #pragma unroll
        for (int k = 0; k < 64; k += 2) {
            const float h0 = rdlane(h, k);
            const float h1 = rdlane(h, k+1);
            a1  = fmaf(wr[k],   h0, a1 );
            a1b = fmaf(wr[k+1], h1, a1b);
            a2  = fmaf(w2[k],   h0, a2 );
            a2b = fmaf(w2[k+1], h1, a2b);
        }
        a1 += a1b; a2 += a2b;
        float az = rdlane(a2, 1);                    // raw row 65
        az = fminf(fmaxf(az, 0.5f), 30.0f);
        const float vv0 = rdlane(a2, 4);             // value row 68
        const float vv1 = rdlane(a2, 5);             // value row 69
        if (j >= 2) wbuf16[b*64 + j - 2]  = f2bf(a1);
        else        wbuf16[b*64 + 62 + j] = f2bf(a2);
        if (j == 2 || j == 3)
            sig_out[b*2 + j - 2] = 1.0f / (1.0f + __expf(-a2)) + 0.001f;
        if (j < 2) {
            const float y0 = (j == 0) ? s0 : s1;
            const float vvl = (j == 0) ? vv0 : vv1;
            *(float4*)(pbuf + (b*2 + j)*4) = make_float4(a1, a1 - y0, az, vvl);
        }
    }
}

// ---------------- kernel C: DMP rollout, MFMA-fed forcing ----------------
// Wave = 16 channels x 4 time-groups; per-lane partial linear state summed
// at flush. Tile transpose via 4x ds_write_b128 + 4x ds_read_b128 per chunk
// (pad-20 rows -> conflict-free start-bank profile). No block barriers:
// tile slices are per-wave, within-wave DS ordering is automatic.
__global__ __launch_bounds__(256) void k_rollout(
    const ushort* __restrict__ phiB, const float* __restrict__ pbuf,
    const ushort* __restrict__ wbuf16, float* __restrict__ a_out,
    float* __restrict__ v_out)
{
    __shared__ float tile[256][20];     // 20 KB
    const int tid = threadIdx.x;
    const int wv = tid >> 6;
    const int l  = tid & 63;
    const int ch = l & 15;
    const int g  = l >> 4;
    const int m  = (blockIdx.x << 6) + (wv << 4) + ch;

    const float4 pp = *(const float4*)(pbuf + m*4);   // {goal, kfac, az, v}
    const float az = pp.z;
    const float Ac = DTF * az * az * 0.25f;
    const float Bc = DTF * az;
    const float Kc = DTF * pp.y;
    const float c0 = (g == 0) ? Ac * pp.x : 0.0f;
    float y = (g == 0) ? (pp.x - pp.y) : 0.0f;        // y0
    float z = (g == 0) ? 0.01f : 0.0f;

    const bf16x8 wb = *(const bf16x8*)(wbuf16 + m*NB + g*8);
    const bf16x8* ap = (const bf16x8*)(phiB + ch*NB + g*8);  // +64 per chunk
    bf16x8 af = ap[0];

    const float fv = pp.w;
    const f32x4 zacc = {0.0f, 0.0f, 0.0f, 0.0f};
    float4* myrow = (float4*)&tile[tid][0];

    for (int c = 0; c < 19; ++c) {
        f32x4 facc = __builtin_amdgcn_mfma_f32_16x16x32_bf16(af, wb, zacc, 0, 0, 0);
        if (c < 18) af = ap[(c + 1) * 64];
        float av[16];
        #pragma unroll
        for (int i = 0; i < 16; ++i) {
            float f = (g == (i >> 2)) ? facc[i & 3] : 0.0f;
            av[i] = z * DTF;
            float u = z + c0;
            u = fmaf(Kc, f, u);
            u = fmaf(-Bc, z, u);
            z = fmaf(-Ac, y, u);
            y += av[i];
        }
        #pragma unroll
        for (int q = 0; q < 4; ++q)
            myrow[q] = make_float4(av[q*4+0], av[q*4+1], av[q*4+2], av[q*4+3]);

        if (c < 18 || g < 3) {
            float4 s4 = make_float4(0.f, 0.f, 0.f, 0.f);
            #pragma unroll
            for (int gg = 0; gg < 4; ++gg) {
                const float4 v4 = *(const float4*)&tile[(wv << 6) + (gg << 4) + ch][g << 2];
                s4.x += v4.x; s4.y += v4.y; s4.z += v4.z; s4.w += v4.w;
            }
            const int ob = m * TS + c*16 + (g << 2);
            *(float4*)(a_out + ob) = s4;
            *(float4*)(v_out + ob) = make_float4(fv, fv, fv, fv);
        }
    }
}

extern "C" void kernel_launch(void* const* d_in, const int* in_sizes, int n_in,
                              void* d_out, int out_size, void* d_ws, size_t ws_size,
                              hipStream_t stream) {
    (void)in_sizes; (void)n_in; (void)out_size; (void)ws_size;
    const float* state  = (const float*)d_in[0];
    const float* fc1_w  = (const float*)d_in[1];
    const float* fc1_b  = (const float*)d_in[2];
    const float* fc2m_w = (const float*)d_in[3];
    const float* fc2m_b = (const float*)d_in[4];
    const float* sig_w  = (const float*)d_in[5];
    const float* sig_b  = (const float*)d_in[6];
    const float* val_w  = (const float*)d_in[7];
    const float* val_b  = (const float*)d_in[8];
    const float* dmp_c  = (const float*)d_in[9];
    const float* dmp_s2 = (const float*)d_in[10];

    float* out     = (float*)d_out;
    float* a_out   = out;
    float* sig_out = out + A_ELEMS;
    float* v_out   = out + A_ELEMS + NBATCH*2;

    float* ws     = (float*)d_ws;
    ushort* phiB  = (ushort*)ws;                     // 19,456 B
    float* pbuf   = ws + 8192;                       // 131,072 floats
    ushort* wbuf16 = (ushort*)(ws + 8192 + 131072);  // 1,048,576 ushorts (2 MB)

    k_head<<<dim3(513), dim3(256), 0, stream>>>(state, fc1_w, fc1_b, fc2m_w, fc2m_b,
                                                sig_w, sig_b, val_w, val_b,
                                                dmp_c, dmp_s2,
                                                sig_out, pbuf, wbuf16, phiB);
    k_rollout<<<dim3(512), dim3(256), 0, stream>>>(phiB, pbuf, wbuf16, a_out, v_out);
}